// Round 6
// baseline (358.260 us; speedup 1.0000x reference)
//
#include <hip/hip_runtime.h>
#include <hip/hip_bf16.h>

typedef short short8 __attribute__((ext_vector_type(8)));
typedef float float4v __attribute__((ext_vector_type(4)));

#define TK 32
#define MAXSPLIT 20
#define APAD 40   // 80 B row stride for bf16 tiles: 16B-aligned frag reads

// gfx950 packed fp32->bf16 (RNE), 1 VALU op for 2 elements.
__device__ __forceinline__ unsigned int pack2bf(float a, float b) {
    unsigned int r;
    asm("v_cvt_pk_bf16_f32 %0, %1, %2" : "=v"(r) : "v"(a), "v"(b));
    return r;
}

// ---------------- K1: split-K bf16 MFMA GEMM: P_mod[b][j] = sum_k A[b,k] * W[j,k] ----------------
// 256x256 tile (2x amplification = 450 MB total operand stream, the minimum for this reg budget).
// Evidence ledger: R1 128^2@12waves/CU sustained 7.0 TB/s; R2 256^2@8waves 1-deep reg-staged = 4.15;
// R5 DMA-to-LDS = 3.6 (barrier vmcnt(0) drain exposes tail latency each step -> never DMA here).
// R3: >2 waves/SIMD impossible (acc alone 128 regs) -> launch_bounds(512,2) is mandatory.
// This version: TRUE 2-deep register pipeline. Loads for step t issued during t-2, packed->LDS
// during t-1, consumed at t. 16 loads/wave in flight at all times (2x R2). Static reg sets
// (stA/stB) via 2x-unrolled loop -- runtime-indexed reg arrays would go to scratch.
__global__ __launch_bounds__(512, 2) void gemm_kernel(
    const float* __restrict__ Ae, const float* __restrict__ Am, const float* __restrict__ Ac,
    const float* __restrict__ Wex, const float* __restrict__ Wey,
    const float* __restrict__ Wmx, const float* __restrict__ Wmy,
    const float* __restrict__ Wcx, const float* __restrict__ Wcy,
    float* __restrict__ part, int nsplit)
{
    // XCD grouping: xcd = bid&7 gets a contiguous job range; consecutive jobs form
    // (mod,split) groups of 4 tiles sharing A/W slabs -> co-resident on one XCD's L2.
    int nb = gridDim.x;                 // 12*nsplit, nsplit even -> divisible by 8
    int per = nb >> 3;
    int bid = blockIdx.x;
    int job = (bid & 7) * per + (bid >> 3);

    int mod = job / (4 * nsplit);
    int rem = job - mod * 4 * nsplit;
    int split = rem >> 2;
    int t2 = rem & 3;
    int ti = t2 >> 1, tj = t2 & 1;

    const float* A; const float* Wx; const float* Wy; int K;
    if (mod == 0)      { A = Ae; Wx = Wex; Wy = Wey; K = 20000; }
    else if (mod == 1) { A = Am; Wx = Wmx; Wy = Wmy; K = 15000; }
    else               { A = Ac; Wx = Wcx; Wy = Wcy; K = 20000; }

    int chunk = ((K + nsplit * TK - 1) / (nsplit * TK)) * TK;
    int kstart = split * chunk;
    int kend = kstart + chunk; if (kend > K) kend = K;
    if (kstart >= kend) return;
    int nstep = (kend - kstart + TK - 1) / TK;

    const float* Abase = A + (size_t)(ti * 256) * K;
    const float* Wbase = (tj == 0) ? Wx : Wy;     // 256 cols = one full W matrix half

    __shared__ unsigned short As[2][256][APAD];   // bf16, padded (40 KB)
    __shared__ unsigned short Bs[2][256][APAD];   // bf16, padded (40 KB)

    int tid = threadIdx.x;
    int lane = tid & 63, w = tid >> 6;
    int wr = (w & 3) * 64;          // 4 row-waves
    int wc = (w >> 2) * 128;        // 2 col-waves
    int r16 = lane & 15, q8 = (lane >> 4) * 8;

    // staging map: thread covers rows ra0 + i*64 (i=0..3), k-granule ca..ca+3
    int ra0 = tid >> 3;             // 0..63
    int ca  = (tid & 7) * 4;

    // st[0..3] = A rows, st[4..7] = W rows
    auto loadInto = [&](float4v (&st)[8], int k0) {
        int k = k0 + ca; if (k > K - 4) k = K - 4;       // clamp; tail zeroed at store
        #pragma unroll
        for (int i = 0; i < 4; ++i) {
            st[i]     = *(const float4v*)(Abase + (size_t)(ra0 + i * 64) * K + k);
            st[4 + i] = *(const float4v*)(Wbase + (size_t)(ra0 + i * 64) * K + k);
        }
    };
    auto storeFrom = [&](float4v (&st)[8], int buf, int k0) {
        bool kill = (k0 + ca >= kend);                   // kend is 4-aligned; whole-granule kill
        #pragma unroll
        for (int i = 0; i < 4; ++i) {
            float4v va = st[i], vb = st[4 + i];
            if (kill) { va = (float4v){0.f,0.f,0.f,0.f}; vb = (float4v){0.f,0.f,0.f,0.f}; }
            uint2 pa, pb;
            pa.x = pack2bf(va[0], va[1]);
            pa.y = pack2bf(va[2], va[3]);
            pb.x = pack2bf(vb[0], vb[1]);
            pb.y = pack2bf(vb[2], vb[3]);
            *(uint2*)&As[buf][ra0 + i * 64][ca] = pa;
            *(uint2*)&Bs[buf][ra0 + i * 64][ca] = pb;
        }
    };

    float4v acc[4][8];
    #pragma unroll
    for (int a = 0; a < 4; ++a)
        #pragma unroll
        for (int b = 0; b < 8; ++b)
            acc[a][b] = (float4v){0.f, 0.f, 0.f, 0.f};

    auto computeStep = [&](int buf) {
        short8 fa[4], fb[8];
        #pragma unroll
        for (int a = 0; a < 4; ++a)
            fa[a] = *(const short8*)&As[buf][wr + a * 16 + r16][q8];
        #pragma unroll
        for (int b = 0; b < 8; ++b)
            fb[b] = *(const short8*)&Bs[buf][wc + b * 16 + r16][q8];
        #pragma unroll
        for (int a = 0; a < 4; ++a)
            #pragma unroll
            for (int b = 0; b < 8; ++b)
                acc[a][b] = __builtin_amdgcn_mfma_f32_16x16x32_bf16(fa[a], fb[b], acc[a][b], 0, 0, 0);
    };

    float4v stA[8], stB[8];

    // prologue: step0 staged to buf0; step1 loads in flight across the barrier
    loadInto(stA, kstart);
    storeFrom(stA, 0, kstart);
    loadInto(stB, kstart + TK);          // harmless (clamped) if nstep == 1
    __syncthreads();

    // steady state (2x unrolled; buffer/regset parity static):
    //   substep0 (step s, buf0):  issue stA loads for s+2 | compute buf0 | pack stB -> buf1
    //   substep1 (step s+1,buf1): issue stB loads for s+3 | compute buf1 | pack stA -> buf0
    // During every compute phase: 16 loads/wave outstanding (steps +1 and +2).
    int s = 0;
    for (; s + 1 < nstep; s += 2) {
        if (s + 2 < nstep) loadInto(stA, kstart + (s + 2) * TK);
        computeStep(0);
        storeFrom(stB, 1, kstart + (s + 1) * TK);   // vmcnt wait: loads issued last substep1
        __syncthreads();

        if (s + 3 < nstep) loadInto(stB, kstart + (s + 3) * TK);
        computeStep(1);
        if (s + 2 < nstep) storeFrom(stA, 0, kstart + (s + 2) * TK);
        __syncthreads();
    }
    if (s < nstep) computeStep(0);       // odd-nstep tail (s even here by construction)

    // partial tile out: part[mod][t2][split][256][256]
    float* pbase = part + (size_t)((mod * 4 + t2) * nsplit + split) * 65536;
    #pragma unroll
    for (int a = 0; a < 4; ++a)
        #pragma unroll
        for (int b = 0; b < 8; ++b)
            #pragma unroll
            for (int r = 0; r < 4; ++r) {
                int row = wr + a * 16 + (lane >> 4) * 4 + r;  // C/D: row = quad*4+reg
                int col = wc + b * 16 + r16;                   // col = lane&15
                pbase[row * 256 + col] = acc[a][b][r];
            }
}

// ---------------- K2: split-K reduction + zero head accumulators ----------------
__global__ void reduce_kernel(const float* __restrict__ part, float* __restrict__ P,
                              float* __restrict__ headacc, int nsplit)
{
    int gid = blockIdx.x * 256 + threadIdx.x;   // 786432 total
    if (gid < 1536) headacc[gid] = 0.f;
    int mod = gid >> 18;
    int rem = gid & 262143;
    int b = rem >> 9, j = rem & 511;
    int ti = b >> 8, r = b & 255, tj = j >> 8, c = j & 255;
    int t2 = ti * 2 + tj;
    const float* src = part + (size_t)((mod * 4 + t2) * nsplit) * 65536 + r * 256 + c;
    float s = 0.f;
    for (int k = 0; k < nsplit; ++k) s += src[(size_t)k * 65536];
    P[gid] = s;
}

// ---------------- K3: per-(batch,pair) fused normalize + rank-2 attention + head partials ----------------
__global__ __launch_bounds__(256) void pairs_kernel(
    const float* __restrict__ P, float* __restrict__ headacc,
    const float* __restrict__ W3e, const float* __restrict__ W3m, const float* __restrict__ W3c)
{
    int b = blockIdx.x / 3, pair = blockIdx.x % 3;   // 0:em 1:ec 2:mc
    int t = threadIdx.x;
    __shared__ float2 Pn[256], Qn[256];
    __shared__ float Rinv[256];
    __shared__ float red[4];

    int pm = (pair == 2) ? 1 : 0;
    int qm = (pair == 0) ? 1 : 2;
    const float* prow = P + pm * 262144 + b * 512;
    const float* qrow = P + qm * 262144 + b * 512;

    float px = prow[t], py = prow[256 + t];
    float ip = rsqrtf(px * px + py * py);
    Pn[t] = (float2){px * ip, py * ip};
    float qx = qrow[t], qy = qrow[256 + t];
    float iq = rsqrtf(qx * qx + qy * qy);
    Qn[t] = (float2){qx * iq, qy * iq};
    __syncthreads();

    const float L2E = 1.4426950408889634f;

    // ---- pass R: thread = row r. rowsum + q-weighted row sums -> B-side output (q's feature) ----
    float pxr = Pn[t].x * L2E, pyr = Pn[t].y * L2E;
    float rs = 0.f, rqx = 0.f, rqy = 0.f;
    #pragma unroll 4
    for (int j = 0; j < 256; ++j) {
        float2 qv = Qn[j];
        float x = exp2f(fmaf(pyr, qv.y, pxr * qv.x));
        rs += x;
        rqx = fmaf(qv.x, x, rqx);
        rqy = fmaf(qv.y, x, rqy);
    }
    float rinv = 1.f / rs;
    Rinv[t] = rinv;
    float Fq0 = rqx * rinv, Fq1 = rqy * rinv;

    const float* WR; int hR, offR;
    if (pair == 0)      { WR = W3m; hR = 1; offR = 0; }   // m_feat chunks 0,1
    else if (pair == 1) { WR = W3c; hR = 2; offR = 0; }   // c_feat chunks 0,1
    else                { WR = W3c; hR = 2; offR = 512; } // c_feat chunks 2,3
    float v = Fq0 * WR[offR + t] + Fq1 * WR[offR + 256 + t];
    #pragma unroll
    for (int o = 32; o > 0; o >>= 1) v += __shfl_down(v, o, 64);
    if ((t & 63) == 0) red[t >> 6] = v;
    __syncthreads();
    if (t == 0) atomicAdd(&headacc[b * 3 + hR], red[0] + red[1] + red[2] + red[3]);
    __syncthreads();

    // ---- pass C: thread = col n. col softmax (A-side) or rowsum-prescaled matmul (mc C-form) ----
    float qxr = Qn[t].x * L2E, qyr = Qn[t].y * L2E;
    float cs = 0.f, cpx = 0.f, cpy = 0.f;
    if (pair < 2) {
        #pragma unroll 4
        for (int i = 0; i < 256; ++i) {
            float2 pv = Pn[i];
            float x = exp2f(fmaf(qyr, pv.y, qxr * pv.x));
            cs += x;
            cpx = fmaf(pv.x, x, cpx);
            cpy = fmaf(pv.y, x, cpy);
        }
        float ci = 1.f / cs;
        cpx *= ci; cpy *= ci;
    } else {
        #pragma unroll 4
        for (int i = 0; i < 256; ++i) {
            float2 pv = Pn[i];
            float x = exp2f(fmaf(qyr, pv.y, qxr * pv.x)) * Rinv[i];
            cpx = fmaf(pv.x, x, cpx);
            cpy = fmaf(pv.y, x, cpy);
        }
    }
    const float* WC; int hC, offC;
    if (pair == 0)      { WC = W3e; hC = 0; offC = 0; }   // e_feat chunks 0,1
    else if (pair == 1) { WC = W3e; hC = 0; offC = 512; } // e_feat chunks 2,3
    else                { WC = W3m; hC = 1; offC = 512; } // m_feat chunks 2,3
    float v2 = cpx * WC[offC + t] + cpy * WC[offC + 256 + t];
    #pragma unroll
    for (int o = 32; o > 0; o >>= 1) v2 += __shfl_down(v2, o, 64);
    if ((t & 63) == 0) red[t >> 6] = v2;
    __syncthreads();
    if (t == 0) atomicAdd(&headacc[b * 3 + hC], red[0] + red[1] + red[2] + red[3]);
}

// ---------------- K4: bias + sigmoid ----------------
__global__ void head_kernel(const float* __restrict__ headacc,
                            const float* __restrict__ b3e, const float* __restrict__ b3m,
                            const float* __restrict__ b3c, float* __restrict__ out)
{
    int i = blockIdx.x * 256 + threadIdx.x;
    if (i >= 1536) return;
    int h = i >> 9, b = i & 511;
    float bias = (h == 0) ? b3e[0] : (h == 1) ? b3m[0] : b3c[0];
    float z = headacc[b * 3 + h] + bias;
    out[i] = 1.f / (1.f + __expf(-z));
}

extern "C" void kernel_launch(void* const* d_in, const int* in_sizes, int n_in,
                              void* d_out, int out_size, void* d_ws, size_t ws_size,
                              hipStream_t stream) {
    const float* Ae  = (const float*)d_in[0];
    const float* Am  = (const float*)d_in[1];
    const float* Ac  = (const float*)d_in[2];
    const float* Wex = (const float*)d_in[3];
    const float* Wey = (const float*)d_in[4];
    const float* Wmx = (const float*)d_in[5];
    const float* Wmy = (const float*)d_in[6];
    const float* Wcx = (const float*)d_in[7];
    const float* Wcy = (const float*)d_in[8];
    const float* W3e = (const float*)d_in[9];
    const float* b3e = (const float*)d_in[10];
    const float* W3m = (const float*)d_in[11];
    const float* b3m = (const float*)d_in[12];
    const float* W3c = (const float*)d_in[13];
    const float* b3c = (const float*)d_in[14];

    // workspace: part[12][nsplit][65536] | P[786432] | headacc[1536]
    size_t fixed = (size_t)786432 * 4 + 1536 * 4;
    int nsplit = 2;
    if (ws_size > fixed) {
        size_t avail = (ws_size - fixed) / ((size_t)12 * 65536 * 4);
        nsplit = (avail < MAXSPLIT) ? (int)avail : MAXSPLIT;
        if (nsplit < 2) nsplit = 2;
    }
    nsplit &= ~1;   // even -> grid 12*nsplit divisible by 8 (XCD swizzle)

    float* part    = (float*)d_ws;
    float* P       = part + (size_t)12 * nsplit * 65536;
    float* headacc = P + 786432;

    gemm_kernel<<<12 * nsplit, 512, 0, stream>>>(Ae, Am, Ac, Wex, Wey, Wmx, Wmy, Wcx, Wcy,
                                                 part, nsplit);
    reduce_kernel<<<3072, 256, 0, stream>>>(part, P, headacc, nsplit);
    pairs_kernel<<<1536, 256, 0, stream>>>(P, headacc, W3e, W3m, W3c);
    head_kernel<<<6, 256, 0, stream>>>(headacc, b3e, b3m, b3c, (float*)d_out);
}

// Round 7
// 352.863 us; speedup vs baseline: 1.0153x; 1.0153x over previous
//
#include <hip/hip_runtime.h>
#include <hip/hip_bf16.h>

typedef short short8 __attribute__((ext_vector_type(8)));
typedef float float4v __attribute__((ext_vector_type(4)));

#define TK 32
#define MAXSPLIT 20

typedef const __attribute__((address_space(1))) void* gas_ptr;
typedef __attribute__((address_space(3))) void* las_ptr;

__device__ __forceinline__ void dma16(const float* g, float* l) {
    // async global->LDS DMA, 16 B/lane; LDS dest = wave-uniform base + lane*16
    __builtin_amdgcn_global_load_lds((gas_ptr)g, (las_ptr)l, 16, 0, 0);
}

// gfx950 packed fp32->bf16 (RNE), 1 VALU op for 2 elements.
__device__ __forceinline__ unsigned int pack2bf(float a, float b) {
    unsigned int r;
    asm("v_cvt_pk_bf16_f32 %0, %1, %2" : "=v"(r) : "v"(a), "v"(b));
    return r;
}

#define WAIT_VMCNT(N) asm volatile("s_waitcnt vmcnt(" #N ")" ::: "memory")
#define WAIT_LGKM0()  asm volatile("s_waitcnt lgkmcnt(0)" ::: "memory")

// ---------------- K1: split-K bf16 MFMA GEMM: P_mod[b][j] = sum_k A[b,k] * W[j,k] ----------------
// 256x256 tile (2x amplification = 450 MB total operand stream).
// Evidence ledger: R1 (12 waves/CU, loads always in flight) sustained 7.0 TB/s; R2 (1 block/CU,
// lockstep reg-staging) 4.15; R5 (DMA + __syncthreads) 3.6 -- the implicit vmcnt(0) drain at
// every barrier empties the memory pipe each step; R6 (2-deep reg pipeline) spilled (acc=128
// regs + 64 staging > 256 budget).
// This version: R5's verified DMA datapath + COUNTED vmcnt across RAW s_barriers (T3/T4 minimum
// form). Per step: issue 8 DMAs for s+1, wait vmcnt(8) (only the 8 older, for s, must land),
// s_barrier, compute, lgkmcnt(0), s_barrier. The 8 new DMAs stay in flight through the whole
// compute phase -> 64 KB/CU permanently outstanding -> latency no longer binds.
// NOTE: never set launch_bounds waves/EU > 2 on this tile (R3 post-mortem).
__global__ __launch_bounds__(512, 2) void gemm_kernel(
    const float* __restrict__ Ae, const float* __restrict__ Am, const float* __restrict__ Ac,
    const float* __restrict__ Wex, const float* __restrict__ Wey,
    const float* __restrict__ Wmx, const float* __restrict__ Wmy,
    const float* __restrict__ Wcx, const float* __restrict__ Wcy,
    float* __restrict__ part, int nsplit)
{
    // XCD grouping: xcd = bid&7 gets a contiguous job range; consecutive jobs form
    // (mod,split) groups of 4 tiles sharing A/W slabs -> co-resident on one XCD's L2.
    int nb = gridDim.x;                 // 12*nsplit, nsplit even -> divisible by 8
    int per = nb >> 3;
    int bid = blockIdx.x;
    int job = (bid & 7) * per + (bid >> 3);

    int mod = job / (4 * nsplit);
    int rem = job - mod * 4 * nsplit;
    int split = rem >> 2;
    int t2 = rem & 3;
    int ti = t2 >> 1, tj = t2 & 1;

    const float* A; const float* Wx; const float* Wy; int K;
    if (mod == 0)      { A = Ae; Wx = Wex; Wy = Wey; K = 20000; }
    else if (mod == 1) { A = Am; Wx = Wmx; Wy = Wmy; K = 15000; }
    else               { A = Ac; Wx = Wcx; Wy = Wcy; K = 20000; }

    int chunk = ((K + nsplit * TK - 1) / (nsplit * TK)) * TK;
    int kstart = split * chunk;
    int kend = kstart + chunk; if (kend > K) kend = K;
    if (kstart >= kend) return;
    int nstep = (kend - kstart + TK - 1) / TK;

    const float* Abase = A + (size_t)(ti * 256) * K;
    const float* Wbase = (tj == 0) ? Wx : Wy;     // 256 cols = one full W matrix half

    // fp32 tiles, linear rows of 32 floats (128 B), XOR-granule swizzle within each row.
    __shared__ float As[2][8192];   // 2 x 32 KB
    __shared__ float Bs[2][8192];   // 2 x 32 KB   (total 128 KB)

    int tid = threadIdx.x;
    int lane = tid & 63, w = tid >> 6;
    int wr = (w & 3) * 64;          // 4 row-waves
    int wc = (w >> 2) * 128;        // 2 col-waves
    int q = lane >> 4, r16 = lane & 15, q8 = q * 8;
    int lrow = lane >> 3, l8 = lane & 7;

    // DMA map (R5-verified): chunk c (1 KB = 8 rows of 32 fp32); wave w covers chunks
    // {w, w+8, w+16, w+24}. lane -> row c*8 + (lane>>3); physical granule lane&7 holds
    // logical granule (l8 ^ (row&7)). 8 DMA instructions per wave per call.
    auto dmaAll = [&](int buf, int k0) {
        #pragma unroll
        for (int i = 0; i < 4; ++i) {
            int c = i * 8 + w;
            int r = c * 8 + lrow;
            int g = l8 ^ (r & 7);
            int k = k0 + g * 4; if (k > K - 4) k = K - 4;   // clamp; tail zeroed at frag read
            dma16(Abase + (size_t)r * K + k, &As[buf][c * 256]);
            dma16(Wbase + (size_t)r * K + k, &Bs[buf][c * 256]);
        }
    };

    float4v acc[4][8];
    #pragma unroll
    for (int a = 0; a < 4; ++a)
        #pragma unroll
        for (int b = 0; b < 8; ++b)
            acc[a][b] = (float4v){0.f, 0.f, 0.f, 0.f};

    auto computeStep = [&](int buf, int k0, bool tail) {
        bool z0 = false, z1 = false;
        if (tail) { z0 = (k0 + q8 >= kend); z1 = (k0 + q8 + 4 >= kend); }
        short8 fa[4], fb[8];
        #pragma unroll
        for (int a = 0; a < 4; ++a) {
            int r = wr + a * 16 + r16;
            int rx = r & 7;
            const float* rowp = &As[buf][r * 32];
            float4v g0 = *(const float4v*)(rowp + (((2 * q)     ^ rx) * 4));
            float4v g1 = *(const float4v*)(rowp + (((2 * q + 1) ^ rx) * 4));
            if (z0) g0 = (float4v){0.f, 0.f, 0.f, 0.f};
            if (z1) g1 = (float4v){0.f, 0.f, 0.f, 0.f};
            union { unsigned int u[4]; short8 s; } pk;
            pk.u[0] = pack2bf(g0[0], g0[1]);
            pk.u[1] = pack2bf(g0[2], g0[3]);
            pk.u[2] = pack2bf(g1[0], g1[1]);
            pk.u[3] = pack2bf(g1[2], g1[3]);
            fa[a] = pk.s;
        }
        #pragma unroll
        for (int b = 0; b < 8; ++b) {
            int r = wc + b * 16 + r16;
            int rx = r & 7;
            const float* rowp = &Bs[buf][r * 32];
            float4v g0 = *(const float4v*)(rowp + (((2 * q)     ^ rx) * 4));
            float4v g1 = *(const float4v*)(rowp + (((2 * q + 1) ^ rx) * 4));
            if (z0) g0 = (float4v){0.f, 0.f, 0.f, 0.f};
            if (z1) g1 = (float4v){0.f, 0.f, 0.f, 0.f};
            union { unsigned int u[4]; short8 s; } pk;
            pk.u[0] = pack2bf(g0[0], g0[1]);
            pk.u[1] = pack2bf(g0[2], g0[3]);
            pk.u[2] = pack2bf(g1[0], g1[1]);
            pk.u[3] = pack2bf(g1[2], g1[3]);
            fb[b] = pk.s;
        }
        #pragma unroll
        for (int a = 0; a < 4; ++a)
            #pragma unroll
            for (int b = 0; b < 8; ++b)
                acc[a][b] = __builtin_amdgcn_mfma_f32_16x16x32_bf16(fa[a], fb[b], acc[a][b], 0, 0, 0);
    };

    // prologue: fire DMAs for step 0
    dmaAll(0, kstart);

    for (int s = 0; s < nstep; ++s) {
        int cur = s & 1;
        int k0 = kstart + s * TK;
        bool more = (s + 1 < nstep);
        if (more) {
            dmaAll(cur ^ 1, k0 + TK);    // overwrites buf read 2 steps ago; safe after barrier-2
            WAIT_VMCNT(8);               // only the 8 OLDER DMAs (for step s) must have landed
        } else {
            WAIT_VMCNT(0);               // no new DMAs issued -> drain the last 8
        }
        __builtin_amdgcn_sched_barrier(0);
        __builtin_amdgcn_s_barrier();    // barrier-1: buf[cur] visible to all waves
        computeStep(cur, k0, k0 + TK > kend);
        WAIT_LGKM0();                    // my ds_reads retired
        __builtin_amdgcn_sched_barrier(0);
        __builtin_amdgcn_s_barrier();    // barrier-2: all reads of buf[cur] done
    }

    // partial tile out: part[mod][t2][split][256][256]
    float* pbase = part + (size_t)((mod * 4 + t2) * nsplit + split) * 65536;
    #pragma unroll
    for (int a = 0; a < 4; ++a)
        #pragma unroll
        for (int b = 0; b < 8; ++b)
            #pragma unroll
            for (int r = 0; r < 4; ++r) {
                int row = wr + a * 16 + q * 4 + r;      // C/D: row = quad*4+reg
                int col = wc + b * 16 + r16;            // col = lane&15
                pbase[row * 256 + col] = acc[a][b][r];
            }
}

// ---------------- K2: split-K reduction + zero head accumulators ----------------
__global__ void reduce_kernel(const float* __restrict__ part, float* __restrict__ P,
                              float* __restrict__ headacc, int nsplit)
{
    int gid = blockIdx.x * 256 + threadIdx.x;   // 786432 total
    if (gid < 1536) headacc[gid] = 0.f;
    int mod = gid >> 18;
    int rem = gid & 262143;
    int b = rem >> 9, j = rem & 511;
    int ti = b >> 8, r = b & 255, tj = j >> 8, c = j & 255;
    int t2 = ti * 2 + tj;
    const float* src = part + (size_t)((mod * 4 + t2) * nsplit) * 65536 + r * 256 + c;
    float s = 0.f;
    for (int k = 0; k < nsplit; ++k) s += src[(size_t)k * 65536];
    P[gid] = s;
}

// ---------------- K3: per-(batch,pair) fused normalize + rank-2 attention + head partials ----------------
__global__ __launch_bounds__(256) void pairs_kernel(
    const float* __restrict__ P, float* __restrict__ headacc,
    const float* __restrict__ W3e, const float* __restrict__ W3m, const float* __restrict__ W3c)
{
    int b = blockIdx.x / 3, pair = blockIdx.x % 3;   // 0:em 1:ec 2:mc
    int t = threadIdx.x;
    __shared__ float2 Pn[256], Qn[256];
    __shared__ float Rinv[256];
    __shared__ float red[4];

    int pm = (pair == 2) ? 1 : 0;
    int qm = (pair == 0) ? 1 : 2;
    const float* prow = P + pm * 262144 + b * 512;
    const float* qrow = P + qm * 262144 + b * 512;

    float px = prow[t], py = prow[256 + t];
    float ip = rsqrtf(px * px + py * py);
    Pn[t] = (float2){px * ip, py * ip};
    float qx = qrow[t], qy = qrow[256 + t];
    float iq = rsqrtf(qx * qx + qy * qy);
    Qn[t] = (float2){qx * iq, qy * iq};
    __syncthreads();

    const float L2E = 1.4426950408889634f;

    // ---- pass R: thread = row r. rowsum + q-weighted row sums -> B-side output (q's feature) ----
    float pxr = Pn[t].x * L2E, pyr = Pn[t].y * L2E;
    float rs = 0.f, rqx = 0.f, rqy = 0.f;
    #pragma unroll 4
    for (int j = 0; j < 256; ++j) {
        float2 qv = Qn[j];
        float x = exp2f(fmaf(pyr, qv.y, pxr * qv.x));
        rs += x;
        rqx = fmaf(qv.x, x, rqx);
        rqy = fmaf(qv.y, x, rqy);
    }
    float rinv = 1.f / rs;
    Rinv[t] = rinv;
    float Fq0 = rqx * rinv, Fq1 = rqy * rinv;

    const float* WR; int hR, offR;
    if (pair == 0)      { WR = W3m; hR = 1; offR = 0; }   // m_feat chunks 0,1
    else if (pair == 1) { WR = W3c; hR = 2; offR = 0; }   // c_feat chunks 0,1
    else                { WR = W3c; hR = 2; offR = 512; } // c_feat chunks 2,3
    float v = Fq0 * WR[offR + t] + Fq1 * WR[offR + 256 + t];
    #pragma unroll
    for (int o = 32; o > 0; o >>= 1) v += __shfl_down(v, o, 64);
    if ((t & 63) == 0) red[t >> 6] = v;
    __syncthreads();
    if (t == 0) atomicAdd(&headacc[b * 3 + hR], red[0] + red[1] + red[2] + red[3]);
    __syncthreads();

    // ---- pass C: thread = col n. col softmax (A-side) or rowsum-prescaled matmul (mc C-form) ----
    float qxr = Qn[t].x * L2E, qyr = Qn[t].y * L2E;
    float cs = 0.f, cpx = 0.f, cpy = 0.f;
    if (pair < 2) {
        #pragma unroll 4
        for (int i = 0; i < 256; ++i) {
            float2 pv = Pn[i];
            float x = exp2f(fmaf(qyr, pv.y, qxr * pv.x));
            cs += x;
            cpx = fmaf(pv.x, x, cpx);
            cpy = fmaf(pv.y, x, cpy);
        }
        float ci = 1.f / cs;
        cpx *= ci; cpy *= ci;
    } else {
        #pragma unroll 4
        for (int i = 0; i < 256; ++i) {
            float2 pv = Pn[i];
            float x = exp2f(fmaf(qyr, pv.y, qxr * pv.x)) * Rinv[i];
            cpx = fmaf(pv.x, x, cpx);
            cpy = fmaf(pv.y, x, cpy);
        }
    }
    const float* WC; int hC, offC;
    if (pair == 0)      { WC = W3e; hC = 0; offC = 0; }   // e_feat chunks 0,1
    else if (pair == 1) { WC = W3e; hC = 0; offC = 512; } // e_feat chunks 2,3
    else                { WC = W3m; hC = 1; offC = 512; } // m_feat chunks 2,3
    float v2 = cpx * WC[offC + t] + cpy * WC[offC + 256 + t];
    #pragma unroll
    for (int o = 32; o > 0; o >>= 1) v2 += __shfl_down(v2, o, 64);
    if ((t & 63) == 0) red[t >> 6] = v2;
    __syncthreads();
    if (t == 0) atomicAdd(&headacc[b * 3 + hC], red[0] + red[1] + red[2] + red[3]);
}

// ---------------- K4: bias + sigmoid ----------------
__global__ void head_kernel(const float* __restrict__ headacc,
                            const float* __restrict__ b3e, const float* __restrict__ b3m,
                            const float* __restrict__ b3c, float* __restrict__ out)
{
    int i = blockIdx.x * 256 + threadIdx.x;
    if (i >= 1536) return;
    int h = i >> 9, b = i & 511;
    float bias = (h == 0) ? b3e[0] : (h == 1) ? b3m[0] : b3c[0];
    float z = headacc[b * 3 + h] + bias;
    out[i] = 1.f / (1.f + __expf(-z));
}

extern "C" void kernel_launch(void* const* d_in, const int* in_sizes, int n_in,
                              void* d_out, int out_size, void* d_ws, size_t ws_size,
                              hipStream_t stream) {
    const float* Ae  = (const float*)d_in[0];
    const float* Am  = (const float*)d_in[1];
    const float* Ac  = (const float*)d_in[2];
    const float* Wex = (const float*)d_in[3];
    const float* Wey = (const float*)d_in[4];
    const float* Wmx = (const float*)d_in[5];
    const float* Wmy = (const float*)d_in[6];
    const float* Wcx = (const float*)d_in[7];
    const float* Wcy = (const float*)d_in[8];
    const float* W3e = (const float*)d_in[9];
    const float* b3e = (const float*)d_in[10];
    const float* W3m = (const float*)d_in[11];
    const float* b3m = (const float*)d_in[12];
    const float* W3c = (const float*)d_in[13];
    const float* b3c = (const float*)d_in[14];

    // workspace: part[12][nsplit][65536] | P[786432] | headacc[1536]
    size_t fixed = (size_t)786432 * 4 + 1536 * 4;
    int nsplit = 2;
    if (ws_size > fixed) {
        size_t avail = (ws_size - fixed) / ((size_t)12 * 65536 * 4);
        nsplit = (avail < MAXSPLIT) ? (int)avail : MAXSPLIT;
        if (nsplit < 2) nsplit = 2;
    }
    nsplit &= ~1;   // even -> grid 12*nsplit divisible by 8 (XCD swizzle)

    float* part    = (float*)d_ws;
    float* P       = part + (size_t)12 * nsplit * 65536;
    float* headacc = P + 786432;

    gemm_kernel<<<12 * nsplit, 512, 0, stream>>>(Ae, Am, Ac, Wex, Wey, Wmx, Wmy, Wcx, Wcy,
                                                 part, nsplit);
    reduce_kernel<<<3072, 256, 0, stream>>>(part, P, headacc, nsplit);
    pairs_kernel<<<1536, 256, 0, stream>>>(P, headacc, W3e, W3m, W3c);
    head_kernel<<<6, 256, 0, stream>>>(headacc, b3e, b3m, b3c, (float*)d_out);
}

// Round 8
// 341.456 us; speedup vs baseline: 1.0492x; 1.0334x over previous
//
#include <hip/hip_runtime.h>
#include <hip/hip_bf16.h>

typedef short short8 __attribute__((ext_vector_type(8)));
typedef float float4v __attribute__((ext_vector_type(4)));

#define TK 32
#define MAXSPLIT 20
#define APAD 40   // 80 B row stride for bf16 tiles: 16B-aligned frag reads

// gfx950 packed fp32->bf16 (RNE), 1 VALU op for 2 elements.
__device__ __forceinline__ unsigned int pack2bf(float a, float b) {
    unsigned int r;
    asm("v_cvt_pk_bf16_f32 %0, %1, %2" : "=v"(r) : "v"(a), "v"(b));
    return r;
}

// ---------------- K1: split-K bf16 MFMA GEMM: P_mod[b][j] = sum_k A[b,k] * W[j,k] ----------------
// 256x256 tile, R2 datapath (reg-staged, pack-on-write, bf16 LDS, 1-deep) -- best measured (108.9us).
// Ledger: R5/R7 fp32-LDS DMA variants = 125-127us (2x ds_read bytes + inner-loop repack);
// R6 2-deep reg pipeline spilled; R7 counted-vmcnt proved request DEPTH is not the limiter.
// Remaining theory: per-CU delivery (7.2 B/cy vs R1's 11.3) is bound by WHERE the 2nd read of
// each slab line is served. This version removes the unverified "xcd = blockIdx&7" assumption:
// blocks read their PHYSICAL XCD id (s_getreg HW_REG_XCC_ID, m09-verified) and pop jobs from
// per-XCD atomic queues, guaranteeing slab-sharing job groups are co-XCD -> 2nd reads hit L2.
// NOTE: never set launch_bounds waves/EU > 2 on this tile (R3 post-mortem: acc alone = 128 VGPRs).
__global__ __launch_bounds__(512, 2) void gemm_kernel(
    const float* __restrict__ Ae, const float* __restrict__ Am, const float* __restrict__ Ac,
    const float* __restrict__ Wex, const float* __restrict__ Wey,
    const float* __restrict__ Wmx, const float* __restrict__ Wmy,
    const float* __restrict__ Wcx, const float* __restrict__ Wcy,
    float* __restrict__ part, int* __restrict__ ctr, int nsplit)
{
    // Per-XCD job queues: queue x owns jobs [x*per, (x+1)*per), jobs ordered in groups of 4
    // sharing A/W slabs. Each block pops from its own XCD's queue; single-pass steal if full
    // (provably succeeds: #blocks == #slots, each block consumes exactly one).
    int nb = gridDim.x;                 // 12*nsplit, nsplit even -> divisible by 8
    int per = nb >> 3;
    __shared__ int sjob;
    if (threadIdx.x == 0) {
        unsigned xcd;
        asm volatile("s_getreg_b32 %0, hwreg(HW_REG_XCC_ID)" : "=s"(xcd));
        xcd &= 7;
        int j = 0;
        #pragma unroll 1
        for (int t = 0; t < 8; ++t) {
            int x = (xcd + t) & 7;
            int pos = atomicAdd(&ctr[x], 1);
            if (pos < per) { j = x * per + pos; break; }
        }
        sjob = j;
    }
    __syncthreads();
    int job = sjob;

    int mod = job / (4 * nsplit);
    int rem = job - mod * 4 * nsplit;
    int split = rem >> 2;
    int t2 = rem & 3;
    int ti = t2 >> 1, tj = t2 & 1;

    const float* A; const float* Wx; const float* Wy; int K;
    if (mod == 0)      { A = Ae; Wx = Wex; Wy = Wey; K = 20000; }
    else if (mod == 1) { A = Am; Wx = Wmx; Wy = Wmy; K = 15000; }
    else               { A = Ac; Wx = Wcx; Wy = Wcy; K = 20000; }

    int chunk = ((K + nsplit * TK - 1) / (nsplit * TK)) * TK;
    int kstart = split * chunk;
    int kend = kstart + chunk; if (kend > K) kend = K;
    if (kstart >= kend) return;
    int nstep = (kend - kstart + TK - 1) / TK;

    const float* Abase = A + (size_t)(ti * 256) * K;
    const float* Wbase = (tj == 0) ? Wx : Wy;     // 256 cols = one full W matrix half

    __shared__ unsigned short As[2][256][APAD];   // bf16, padded (40 KB)
    __shared__ unsigned short Bs[2][256][APAD];   // bf16, padded (40 KB)

    int tid = threadIdx.x;
    int lane = tid & 63, w = tid >> 6;
    int wr = (w & 3) * 64;          // 4 row-waves
    int wc = (w >> 2) * 128;        // 2 col-waves
    int q = lane >> 4, r16 = lane & 15, q8 = q * 8;

    // staging map: thread covers rows ra0 + i*64 (i=0..3), k-granule ca..ca+3
    int ra0 = tid >> 3;             // 0..63
    int ca  = (tid & 7) * 4;

    float4v ar[4], br[4];
    auto loadAB = [&](int k0) {
        int k = k0 + ca; if (k > K - 4) k = K - 4;       // clamp; tail zeroed at store
        #pragma unroll
        for (int i = 0; i < 4; ++i) {
            ar[i] = *(const float4v*)(Abase + (size_t)(ra0 + i * 64) * K + k);
            br[i] = *(const float4v*)(Wbase + (size_t)(ra0 + i * 64) * K + k);
        }
    };
    auto storeAB = [&](int buf, int k0, bool tail) {
        bool kill = tail && (k0 + ca >= kend);
        #pragma unroll
        for (int i = 0; i < 4; ++i) {
            float4v va = ar[i], vb = br[i];
            if (kill) { va = (float4v){0.f,0.f,0.f,0.f}; vb = (float4v){0.f,0.f,0.f,0.f}; }
            uint2 pa, pb;
            pa.x = pack2bf(va[0], va[1]);
            pa.y = pack2bf(va[2], va[3]);
            pb.x = pack2bf(vb[0], vb[1]);
            pb.y = pack2bf(vb[2], vb[3]);
            *(uint2*)&As[buf][ra0 + i * 64][ca] = pa;
            *(uint2*)&Bs[buf][ra0 + i * 64][ca] = pb;
        }
    };

    float4v acc[4][8];
    #pragma unroll
    for (int a = 0; a < 4; ++a)
        #pragma unroll
        for (int b = 0; b < 8; ++b)
            acc[a][b] = (float4v){0.f, 0.f, 0.f, 0.f};

    auto computeStep = [&](int buf) {
        short8 fa[4], fb[8];
        #pragma unroll
        for (int a = 0; a < 4; ++a)
            fa[a] = *(const short8*)&As[buf][wr + a * 16 + r16][q8];
        #pragma unroll
        for (int b = 0; b < 8; ++b)
            fb[b] = *(const short8*)&Bs[buf][wc + b * 16 + r16][q8];
        #pragma unroll
        for (int a = 0; a < 4; ++a)
            #pragma unroll
            for (int b = 0; b < 8; ++b)
                acc[a][b] = __builtin_amdgcn_mfma_f32_16x16x32_bf16(fa[a], fb[b], acc[a][b], 0, 0, 0);
    };

    // prologue: stage step 0
    loadAB(kstart);
    storeAB(0, kstart, kstart + TK > kend);

    for (int s = 0; s < nstep; ++s) {
        int cur = s & 1;
        int k1 = kstart + (s + 1) * TK;
        bool more = (s + 1 < nstep);
        if (more) loadAB(k1);            // issue early; latency overlaps barrier+compute
        __syncthreads();                 // buf[cur] writes visible; all reads of cur^1 done
        computeStep(cur);
        if (more) storeAB(cur ^ 1, k1, k1 + TK > kend);  // vmcnt wait lands after compute
    }

    // partial tile out: part[mod][t2][split][256][256]
    float* pbase = part + (size_t)((mod * 4 + t2) * nsplit + split) * 65536;
    #pragma unroll
    for (int a = 0; a < 4; ++a)
        #pragma unroll
        for (int b = 0; b < 8; ++b)
            #pragma unroll
            for (int r = 0; r < 4; ++r) {
                int row = wr + a * 16 + q * 4 + r;      // C/D: row = quad*4+reg
                int col = wc + b * 16 + r16;            // col = lane&15
                pbase[row * 256 + col] = acc[a][b][r];
            }
}

// ---------------- K2: split-K reduction + zero head accumulators ----------------
__global__ void reduce_kernel(const float* __restrict__ part, float* __restrict__ P,
                              float* __restrict__ headacc, int nsplit)
{
    int gid = blockIdx.x * 256 + threadIdx.x;   // 786432 total
    if (gid < 1536) headacc[gid] = 0.f;
    int mod = gid >> 18;
    int rem = gid & 262143;
    int b = rem >> 9, j = rem & 511;
    int ti = b >> 8, r = b & 255, tj = j >> 8, c = j & 255;
    int t2 = ti * 2 + tj;
    const float* src = part + (size_t)((mod * 4 + t2) * nsplit) * 65536 + r * 256 + c;
    float s = 0.f;
    for (int k = 0; k < nsplit; ++k) s += src[(size_t)k * 65536];
    P[gid] = s;
}

// ---------------- K3: per-(batch,pair) fused normalize + rank-2 attention + head partials ----------------
__global__ __launch_bounds__(256) void pairs_kernel(
    const float* __restrict__ P, float* __restrict__ headacc,
    const float* __restrict__ W3e, const float* __restrict__ W3m, const float* __restrict__ W3c)
{
    int b = blockIdx.x / 3, pair = blockIdx.x % 3;   // 0:em 1:ec 2:mc
    int t = threadIdx.x;
    __shared__ float2 Pn[256], Qn[256];
    __shared__ float Rinv[256];
    __shared__ float red[4];

    int pm = (pair == 2) ? 1 : 0;
    int qm = (pair == 0) ? 1 : 2;
    const float* prow = P + pm * 262144 + b * 512;
    const float* qrow = P + qm * 262144 + b * 512;

    float px = prow[t], py = prow[256 + t];
    float ip = rsqrtf(px * px + py * py);
    Pn[t] = (float2){px * ip, py * ip};
    float qx = qrow[t], qy = qrow[256 + t];
    float iq = rsqrtf(qx * qx + qy * qy);
    Qn[t] = (float2){qx * iq, qy * iq};
    __syncthreads();

    const float L2E = 1.4426950408889634f;

    // ---- pass R: thread = row r. rowsum + q-weighted row sums -> B-side output (q's feature) ----
    float pxr = Pn[t].x * L2E, pyr = Pn[t].y * L2E;
    float rs = 0.f, rqx = 0.f, rqy = 0.f;
    #pragma unroll 4
    for (int j = 0; j < 256; ++j) {
        float2 qv = Qn[j];
        float x = exp2f(fmaf(pyr, qv.y, pxr * qv.x));
        rs += x;
        rqx = fmaf(qv.x, x, rqx);
        rqy = fmaf(qv.y, x, rqy);
    }
    float rinv = 1.f / rs;
    Rinv[t] = rinv;
    float Fq0 = rqx * rinv, Fq1 = rqy * rinv;

    const float* WR; int hR, offR;
    if (pair == 0)      { WR = W3m; hR = 1; offR = 0; }   // m_feat chunks 0,1
    else if (pair == 1) { WR = W3c; hR = 2; offR = 0; }   // c_feat chunks 0,1
    else                { WR = W3c; hR = 2; offR = 512; } // c_feat chunks 2,3
    float v = Fq0 * WR[offR + t] + Fq1 * WR[offR + 256 + t];
    #pragma unroll
    for (int o = 32; o > 0; o >>= 1) v += __shfl_down(v, o, 64);
    if ((t & 63) == 0) red[t >> 6] = v;
    __syncthreads();
    if (t == 0) atomicAdd(&headacc[b * 3 + hR], red[0] + red[1] + red[2] + red[3]);
    __syncthreads();

    // ---- pass C: thread = col n. col softmax (A-side) or rowsum-prescaled matmul (mc C-form) ----
    float qxr = Qn[t].x * L2E, qyr = Qn[t].y * L2E;
    float cs = 0.f, cpx = 0.f, cpy = 0.f;
    if (pair < 2) {
        #pragma unroll 4
        for (int i = 0; i < 256; ++i) {
            float2 pv = Pn[i];
            float x = exp2f(fmaf(qyr, pv.y, qxr * pv.x));
            cs += x;
            cpx = fmaf(pv.x, x, cpx);
            cpy = fmaf(pv.y, x, cpy);
        }
        float ci = 1.f / cs;
        cpx *= ci; cpy *= ci;
    } else {
        #pragma unroll 4
        for (int i = 0; i < 256; ++i) {
            float2 pv = Pn[i];
            float x = exp2f(fmaf(qyr, pv.y, qxr * pv.x)) * Rinv[i];
            cpx = fmaf(pv.x, x, cpx);
            cpy = fmaf(pv.y, x, cpy);
        }
    }
    const float* WC; int hC, offC;
    if (pair == 0)      { WC = W3e; hC = 0; offC = 0; }   // e_feat chunks 0,1
    else if (pair == 1) { WC = W3e; hC = 0; offC = 512; } // e_feat chunks 2,3
    else                { WC = W3m; hC = 1; offC = 512; } // m_feat chunks 2,3
    float v2 = cpx * WC[offC + t] + cpy * WC[offC + 256 + t];
    #pragma unroll
    for (int o = 32; o > 0; o >>= 1) v2 += __shfl_down(v2, o, 64);
    if ((t & 63) == 0) red[t >> 6] = v2;
    __syncthreads();
    if (t == 0) atomicAdd(&headacc[b * 3 + hC], red[0] + red[1] + red[2] + red[3]);
}

// ---------------- K4: bias + sigmoid ----------------
__global__ void head_kernel(const float* __restrict__ headacc,
                            const float* __restrict__ b3e, const float* __restrict__ b3m,
                            const float* __restrict__ b3c, float* __restrict__ out)
{
    int i = blockIdx.x * 256 + threadIdx.x;
    if (i >= 1536) return;
    int h = i >> 9, b = i & 511;
    float bias = (h == 0) ? b3e[0] : (h == 1) ? b3m[0] : b3c[0];
    float z = headacc[b * 3 + h] + bias;
    out[i] = 1.f / (1.f + __expf(-z));
}

extern "C" void kernel_launch(void* const* d_in, const int* in_sizes, int n_in,
                              void* d_out, int out_size, void* d_ws, size_t ws_size,
                              hipStream_t stream) {
    const float* Ae  = (const float*)d_in[0];
    const float* Am  = (const float*)d_in[1];
    const float* Ac  = (const float*)d_in[2];
    const float* Wex = (const float*)d_in[3];
    const float* Wey = (const float*)d_in[4];
    const float* Wmx = (const float*)d_in[5];
    const float* Wmy = (const float*)d_in[6];
    const float* Wcx = (const float*)d_in[7];
    const float* Wcy = (const float*)d_in[8];
    const float* W3e = (const float*)d_in[9];
    const float* b3e = (const float*)d_in[10];
    const float* W3m = (const float*)d_in[11];
    const float* b3m = (const float*)d_in[12];
    const float* W3c = (const float*)d_in[13];
    const float* b3c = (const float*)d_in[14];

    // workspace: part[12][nsplit][65536] | P[786432] | headacc[1536] | ctr[8]
    size_t fixed = (size_t)786432 * 4 + 1536 * 4 + 8 * 4;
    int nsplit = 2;
    if (ws_size > fixed) {
        size_t avail = (ws_size - fixed) / ((size_t)12 * 65536 * 4);
        nsplit = (avail < MAXSPLIT) ? (int)avail : MAXSPLIT;
        if (nsplit < 2) nsplit = 2;
    }
    nsplit &= ~1;   // even -> grid 12*nsplit divisible by 8 (per-XCD queues)

    float* part    = (float*)d_ws;
    float* P       = part + (size_t)12 * nsplit * 65536;
    float* headacc = P + 786432;
    int*   ctr     = (int*)(headacc + 1536);

    hipMemsetAsync(ctr, 0, 8 * sizeof(int), stream);
    gemm_kernel<<<12 * nsplit, 512, 0, stream>>>(Ae, Am, Ac, Wex, Wey, Wmx, Wmy, Wcx, Wcy,
                                                 part, ctr, nsplit);
    reduce_kernel<<<3072, 256, 0, stream>>>(part, P, headacc, nsplit);
    pairs_kernel<<<1536, 256, 0, stream>>>(P, headacc, W3e, W3m, W3c);
    head_kernel<<<6, 256, 0, stream>>>(headacc, b3e, b3m, b3c, (float*)d_out);
}